// Round 8
// baseline (1402.479 us; speedup 1.0000x reference)
//
#include <hip/hip_runtime.h>

// ---- problem constants -------------------------------------------------
#define Bn 2
#define Sn 2048
#define Hn 3584
#define NHn 28
#define NKVn 4
#define HDn 128
#define GROUPSn 7
#define SCALEF 0.08838834764831845f
#define NOUT 14680064LL /* B*S*H */

typedef __attribute__((ext_vector_type(4))) float f4v;
typedef __attribute__((ext_vector_type(8))) short bf16x8;
typedef __attribute__((ext_vector_type(4))) short s16x4;

typedef __attribute__((address_space(1))) void gvoid;
typedef __attribute__((address_space(3))) void lvoid;
#define GLL16(g, l) __builtin_amdgcn_global_load_lds((gvoid*)(void*)(g), (lvoid*)(l), 16, 0, 0)

__device__ __forceinline__ short f2bf(float f) {
  unsigned u = __builtin_bit_cast(unsigned, f);
  u = (u + 0x7fffu + ((u >> 16) & 1u)) >> 16;  // RTNE
  return (short)u;
}

// ---- cast / small prep kernels ----------------------------------------
__global__ __launch_bounds__(256) void cast_bf16(const float* __restrict__ in,
                                                 short* __restrict__ out, long long n4) {
  long long i = (long long)blockIdx.x * 256 + threadIdx.x;
  long long stride = (long long)gridDim.x * 256;
  for (; i < n4; i += stride) {
    f4v f = ((const f4v*)in)[i];
    s16x4 o = { f2bf(f.x), f2bf(f.y), f2bf(f.z), f2bf(f.w) };
    ((s16x4*)out)[i] = o;
  }
}

__global__ __launch_bounds__(256) void concat_bias(const float* __restrict__ bq,
                                                   const float* __restrict__ bk,
                                                   const float* __restrict__ bv,
                                                   float* __restrict__ out) {
  int i = blockIdx.x * 256 + threadIdx.x;
  if (i < 3584) out[i] = bq[i];
  else if (i < 4096) out[i] = bk[i - 3584];
  else if (i < 4608) out[i] = bv[i - 4096];
}

// ---- shared 128x128 bf16 MFMA GEMM core (m97 structure, BK=32) --------
__device__ __forceinline__ void mm128_core(const short* __restrict__ Atile, long long lda,
                                           const short* __restrict__ Btile, long long ldb,
                                           int nk, short* lA, short* lB, f4v (&acc)[4][4]) {
  const int tid = threadIdx.x;
  const int lane = tid & 63;
  const int wr = (tid >> 6) >> 1, wc = (tid >> 6) & 1;
  const int srow = tid >> 2;
  const int scol = (tid & 3) * 8;
  const short* a0 = Atile + (long long)srow * lda + scol;
  const short* a1 = Atile + (long long)(srow + 64) * lda + scol;
  const short* b0 = Btile + (long long)srow * ldb + scol;
  const short* b1 = Btile + (long long)(srow + 64) * ldb + scol;
  short* la0 = lA + tid * 8;
  short* la1 = lA + (256 + tid) * 8;
  short* lb0 = lB + tid * 8;
  short* lb1 = lB + (256 + tid) * 8;
  const int fr = lane & 15;
  const int kc = (lane >> 4) * 8;
  for (int kt = 0; kt < nk; ++kt) {
    GLL16(a0 + kt * 32, la0);
    GLL16(a1 + kt * 32, la1);
    GLL16(b0 + kt * 32, lb0);
    GLL16(b1 + kt * 32, lb1);
    __syncthreads();
    bf16x8 af[4], bf[4];
#pragma unroll
    for (int m = 0; m < 4; ++m)
      af[m] = *(const bf16x8*)&lA[(wr * 64 + m * 16 + fr) * 32 + kc];
#pragma unroll
    for (int n = 0; n < 4; ++n)
      bf[n] = *(const bf16x8*)&lB[(wc * 64 + n * 16 + fr) * 32 + kc];
#pragma unroll
    for (int m = 0; m < 4; ++m)
#pragma unroll
      for (int n = 0; n < 4; ++n)
        acc[m][n] = __builtin_amdgcn_mfma_f32_16x16x32_bf16(af[m], bf[n], acc[m][n], 0, 0, 0);
    __syncthreads();
  }
}

// ---- GEMM with optional bias, fp32 out (QKV proj and Wo proj) ---------
__global__ __launch_bounds__(256) void gemm_bias_f32(const short* __restrict__ A,
                                                     const short* __restrict__ B,
                                                     float* __restrict__ C,
                                                     const float* __restrict__ bias,
                                                     int K, int N) {
  __shared__ alignas(16) short lA[4096];
  __shared__ alignas(16) short lB[4096];
  const long long brow = (long long)blockIdx.y * 128;
  const long long bcol = (long long)blockIdx.x * 128;
  f4v acc[4][4] = {};
  mm128_core(A + brow * K, K, B + bcol * K, K, K >> 5, lA, lB, acc);
  const int lane = threadIdx.x & 63;
  const int wr = (threadIdx.x >> 6) >> 1, wc = (threadIdx.x >> 6) & 1;
  const int rr = (lane >> 4) * 4, cc = lane & 15;
#pragma unroll
  for (int n = 0; n < 4; ++n) {
    long long col = bcol + wc * 64 + n * 16 + cc;
    float bv = bias ? bias[col] : 0.f;
#pragma unroll
    for (int m = 0; m < 4; ++m) {
#pragma unroll
      for (int j = 0; j < 4; ++j) {
        long long row = brow + wr * 64 + m * 16 + rr + j;
        C[row * N + col] = acc[m][n][j] + bv;
      }
    }
  }
}

// ---- RoPE on q,k (reads fp32 qkv, writes bf16 (b,h,s,d)) --------------
__global__ __launch_bounds__(256) void rope_qk(const float* __restrict__ qkv,
                                               const float* __restrict__ cosb,
                                               const float* __restrict__ sinb,
                                               short* __restrict__ qo,
                                               short* __restrict__ ko) {
  long long bs = blockIdx.x;              // 0..B*S-1
  int b = (int)(bs >> 11);
  int s = (int)(bs & 2047);
  const float* row = qkv + bs * 4608;
  const float* cp = cosb + bs * 128;
  const float* sp = sinb + bs * 128;
  for (int i = threadIdx.x; i < 4096; i += 256) {
    int d = i & 127;
    float c = cp[d], sn = sp[d];
    float x = row[i];
    float xr = (d < 64) ? -row[i + 64] : row[i - 64];
    short v = f2bf(x * c + xr * sn);
    if (i < 3584) {
      int h = i >> 7;
      qo[(((long long)(b * NHn + h) * Sn + s)) * HDn + d] = v;
    } else {
      int h = (i - 3584) >> 7;
      ko[(((long long)(b * NKVn + h) * Sn + s)) * HDn + d] = v;
    }
  }
}

// ---- v transpose: qkv fp32 v-section (b,s,kv,d) -> vT bf16 (b,kv,d,s) -
__global__ void vtrans(const float* __restrict__ qkv, short* __restrict__ vt) {
  __shared__ float tile[32][33];
  int bh = blockIdx.z;                    // b*NKV+kv
  int b = bh >> 2, h = bh & 3;
  int s0 = blockIdx.x * 32, d0 = blockIdx.y * 32;
  int tx = threadIdx.x, ty = threadIdx.y;  // 32 x 8
#pragma unroll
  for (int j = 0; j < 32; j += 8) {
    int s = s0 + ty + j;
    tile[ty + j][tx] = qkv[((long long)(b * Sn + s)) * 4608 + 4096 + h * 128 + d0 + tx];
  }
  __syncthreads();
#pragma unroll
  for (int j = 0; j < 32; j += 8) {
    int d = d0 + ty + j;
    vt[((long long)(bh * 128 + d)) * Sn + s0 + tx] = f2bf(tile[tx][ty + j]);
  }
}

// ---- kernel A: one-pass scores, NO-MAX softmax ------------------------
__global__ __launch_bounds__(256) void flash_scores(const short* __restrict__ Q,
                                                    const short* __restrict__ Kb,
                                                    float* __restrict__ probs,
                                                    float* __restrict__ lf) {
  __shared__ alignas(16) short lK[2][16384];   // 2 x 32 KB
  const int tid = threadIdx.x;
  const int w = tid >> 6, lane = tid & 63;
  const int fr = lane & 15, g = lane >> 4;
  const int qb = 15 - (int)blockIdx.x;         // heavy blocks dispatch first
  const int bh = blockIdx.y;
  const int b = bh / NHn, h = bh - b * NHn, kv = h / GROUPSn;
  const short* Qb = Q + (long long)bh * (Sn * HDn);
  const short* Kbb = Kb + (long long)(b * NKVn + kv) * (Sn * HDn);
  float* Pb = probs + (long long)bh * ((long long)Sn * Sn) + (long long)qb * 128 * Sn;

  bf16x8 qf[4][2];
  {
    const short* qr = Qb + (long long)(qb * 128 + w * 32 + fr) * HDn + g * 8;
#pragma unroll
    for (int m = 0; m < 2; ++m)
#pragma unroll
      for (int kk = 0; kk < 4; ++kk)
        qf[kk][m] = *(const bf16x8*)(qr + m * 16 * HDn + kk * 32);
  }

  int rsw[8], csw[8];
#pragma unroll
  for (int i = 0; i < 8; ++i) {
    int M = i * 256 + w * 64 + lane;
    rsw[i] = M >> 4;
    csw[i] = (M & 15) ^ (rsw[i] & 7);
  }

  float lsum[2][4];
#pragma unroll
  for (int m = 0; m < 2; ++m)
#pragma unroll
    for (int j = 0; j < 4; ++j) lsum[m][j] = 0.f;

  const int nkt = qb + 1;
  int cur = 0;
#pragma unroll
  for (int i = 0; i < 8; ++i)
    GLL16(Kbb + (long long)rsw[i] * HDn + csw[i] * 8,
          (short*)lK[0] + i * 2048 + w * 512 + (lane & 63) * 8);

  for (int kt = 0; kt < nkt; ++kt) {
    __syncthreads();
    if (kt + 1 < nkt) {
      const short* base = Kbb + (long long)(kt + 1) * 128 * HDn;
      short* ldst = (short*)lK[cur ^ 1];
#pragma unroll
      for (int i = 0; i < 8; ++i)
        GLL16(base + (long long)rsw[i] * HDn + csw[i] * 8,
              ldst + i * 2048 + w * 512 + (lane & 63) * 8);
    }
    const short* lcur = (const short*)lK[cur];
    f4v acc[2][8] = {};
#pragma unroll
    for (int kk = 0; kk < 4; ++kk) {
      bf16x8 bfv[8];
#pragma unroll
      for (int n = 0; n < 8; ++n) {
        int row = n * 16 + fr;
        int cs = ((kk * 4 + g) ^ (row & 7)) * 8;
        bfv[n] = *(const bf16x8*)&lcur[row * 128 + cs];
      }
#pragma unroll
      for (int m = 0; m < 2; ++m)
#pragma unroll
        for (int n = 0; n < 8; ++n)
          acc[m][n] = __builtin_amdgcn_mfma_f32_16x16x32_bf16(qf[kk][m], bfv[n], acc[m][n], 0, 0, 0);
    }
    const bool diag = (kt == qb);
#pragma unroll
    for (int m = 0; m < 2; ++m) {
#pragma unroll
      for (int j = 0; j < 4; ++j) {
        const int rowl = w * 32 + m * 16 + g * 4 + j;
        float* prow = Pb + (long long)rowl * Sn + kt * 128 + fr;
        float ls = 0.f;
#pragma unroll
        for (int n = 0; n < 8; ++n) {
          float s = fminf(acc[m][n][j] * SCALEF, 60.f);
          float p = __expf(s);
          if (diag && (n * 16 + fr) > rowl) p = 0.f;
          ls += p;
          prow[n * 16] = p;
        }
        lsum[m][j] += ls;
      }
    }
    cur ^= 1;
  }
#pragma unroll
  for (int m = 0; m < 2; ++m)
#pragma unroll
    for (int j = 0; j < 4; ++j) {
      float v = lsum[m][j];
      v += __shfl_xor(v, 1);
      v += __shfl_xor(v, 2);
      v += __shfl_xor(v, 4);
      v += __shfl_xor(v, 8);
      if (fr == 0) {
        const int rowl = w * 32 + m * 16 + g * 4 + j;
        lf[(long long)bh * 2048 + qb * 128 + rowl] = v;
      }
    }
}

// ---- kernel B: streaming normalize + causal zeros ---------------------
// One wave per row: cols<=q scaled by 1/l (regular stores), cols>q zeroed
// (nontemporal). Pure streaming: 470MB R + 940MB W, no barriers/MFMA.
__global__ __launch_bounds__(256) void normalize_probs(float* __restrict__ probs,
                                                       const float* __restrict__ lf) {
  const int wid = threadIdx.x >> 6, lane = threadIdx.x & 63;
  long long row = (long long)blockIdx.x * 4 + wid;   // (bh,q) flat, 114688 rows
  int q = (int)(row & (Sn - 1));
  int len = q + 1;
  float inv = 1.f / lf[row];
  float* base = probs + row * Sn;
#pragma unroll
  for (int i = 0; i < 8; ++i) {
    int c = i * 64 + lane;            // f4v chunk index (512 per row)
    int i0 = c * 4;
    if (i0 + 3 < len) {
      f4v v = ((const f4v*)base)[c];
      ((f4v*)base)[c] = v * inv;
    } else if (i0 < len) {
      f4v t = ((const f4v*)base)[c];
      f4v v;
      v.x = (i0 + 0 < len) ? t.x * inv : 0.f;
      v.y = (i0 + 1 < len) ? t.y * inv : 0.f;
      v.z = (i0 + 2 < len) ? t.z * inv : 0.f;
      v.w = (i0 + 3 < len) ? t.w * inv : 0.f;
      ((f4v*)base)[c] = v;
    } else {
      f4v z = {0.f, 0.f, 0.f, 0.f};
      __builtin_nontemporal_store(z, &((f4v*)base)[c]);
    }
  }
}

// ---- kernel C: deep-pipelined PV (NO stores in loop) ------------------
// Reads NORMALIZED P via GLL16 5-buffer ring, 3 tiles in flight; V direct
// to regs. Per-iter VMEM = 2 stage + 8 V loads only -> in-order vmcnt
// retirement is never blocked by store acks. vmcnt(24) = exact-safe min
// younger-op count (tail iters issue no stage). Raw s_barrier (no drain).
__global__ __launch_bounds__(256) void pv_stream(const float* __restrict__ probs,
                                                 const short* __restrict__ Vt,
                                                 short* __restrict__ attn) {
  __shared__ alignas(16) float lP[5][2048];    // 5 x 8 KB ring
  const int tid = threadIdx.x;
  const int lane = tid & 63;
  const int w = tid >> 6;
  const int fr = lane & 15, g = lane >> 4;
  const int bh = blockIdx.y;
  const int b = bh / NHn, h = bh - b * NHn, kv = h / GROUPSn;
  const int qb2 = 31 - (int)blockIdx.x;        // heavy first
  const long long brow = (long long)qb2 * 64;
  const float* A = probs + (long long)bh * ((long long)Sn * Sn) + brow * Sn;
  const short* Bv = Vt + (long long)(b * NKVn + kv) * (HDn * Sn);
  const int nk = 2 * qb2 + 2;                  // k-tiles of 32 (even)
  const int rloc = w * 16 + fr;
  // staging map (both-sides swizzle): LDS slot s -> row s>>3, src col (s&7)^(row&7)
  const int sr0 = tid >> 3;
  const int sc0 = (tid & 7) ^ (sr0 & 7);
  // read slots for row rloc, k-chunk g*8..g*8+7
  const int sl0 = (g * 2) ^ (fr & 7);
  const int sl1 = (g * 2 + 1) ^ (fr & 7);

#define STAGEP(T) do { int tt_ = (T); float* dst_ = &lP[tt_ % 5][0];              \
    GLL16(A + (long long)sr0 * Sn + tt_ * 32 + sc0 * 4, dst_ + tid * 4);          \
    GLL16(A + (long long)(sr0 + 32) * Sn + tt_ * 32 + sc0 * 4,                    \
          dst_ + (256 + tid) * 4);                                                \
  } while (0)

#define LOADV(VR, T) do { int tv_ = (T);                                          \
    _Pragma("unroll")                                                             \
    for (int n = 0; n < 8; ++n)                                                   \
      VR[n] = *(const bf16x8*)(Bv + (long long)(n * 16 + fr) * Sn + tv_ * 32 + g * 8); \
  } while (0)

  f4v acc[8] = {};
  bf16x8 vA[8], vB[8];
  // prologue: 3 P tiles + 2 V tiles, full drain
  STAGEP(0);
  STAGEP(1 < nk ? 1 : nk - 1);
  STAGEP(2 < nk ? 2 : nk - 1);
  LOADV(vA, 0);
  LOADV(vB, 1 < nk ? 1 : nk - 1);
  asm volatile("s_waitcnt vmcnt(0)" ::: "memory");
  __builtin_amdgcn_s_barrier();
  __builtin_amdgcn_sched_barrier(0);

  // younger-than-stage(t) ops: steady 8+10+10+2=30; tail min = 8+8+8+0 = 24.
#define PVITER(VC, T) do { int t_ = (T);                                          \
    if (t_ + 3 < nk) STAGEP(t_ + 3);                                              \
    asm volatile("s_waitcnt vmcnt(24)" ::: "memory");                             \
    __builtin_amdgcn_s_barrier();                                                 \
    __builtin_amdgcn_sched_barrier(0);                                            \
    const float* lbuf_ = &lP[t_ % 5][0];                                          \
    f4v p0_ = *(const f4v*)(lbuf_ + rloc * 32 + sl0 * 4);                         \
    f4v p1_ = *(const f4v*)(lbuf_ + rloc * 32 + sl1 * 4);                         \
    bf16x8 pf_ = (bf16x8){ f2bf(p0_.x), f2bf(p0_.y), f2bf(p0_.z), f2bf(p0_.w),    \
                           f2bf(p1_.x), f2bf(p1_.y), f2bf(p1_.z), f2bf(p1_.w) };  \
    _Pragma("unroll")                                                             \
    for (int n = 0; n < 8; ++n)                                                   \
      acc[n] = __builtin_amdgcn_mfma_f32_16x16x32_bf16(pf_, VC[n], acc[n], 0, 0, 0); \
    LOADV(VC, (t_ + 2 < nk) ? t_ + 2 : nk - 1);                                   \
  } while (0)

  for (int t = 0; t < nk; t += 2) {
    PVITER(vA, t);
    PVITER(vB, t + 1);
  }
#undef PVITER
#undef LOADV
#undef STAGEP

  // attn epilogue (b, q, h*128+d) bf16
#pragma unroll
  for (int n = 0; n < 8; ++n)
#pragma unroll
    for (int j = 0; j < 4; ++j) {
      long long q = brow + w * 16 + g * 4 + j;
      attn[((long long)(b * Sn) + q) * Hn + h * HDn + n * 16 + fr] = f2bf(acc[n][j]);
    }
}

// ---- workspace layout (bytes) -----------------------------------------
// hs_bf16   @ 0          (29,360,128)  -- reused later as attn_bf16
// wqkv_bf16 @ 29,360,128 (33,030,144)  -- reused later as q_bf16
// wo_bf16   @ 62,390,272 (25,690,112)
// bias_qkv  @ 88,080,384 (18,432)
// qkv_f32   @ 88,098,816 (75,497,472)  -- reused after vtrans as lf
// k_bf16    @163,596,288 ( 4,194,304)
// vT_bf16   @167,790,592 ( 4,194,304)   total = 171,984,896 B

extern "C" void kernel_launch(void* const* d_in, const int* in_sizes, int n_in,
                              void* d_out, int out_size, void* d_ws, size_t ws_size,
                              hipStream_t stream) {
  const float* hs   = (const float*)d_in[0];
  const float* cosb = (const float*)d_in[1];
  const float* sinb = (const float*)d_in[2];
  // d_in[3] attention_mask: exact causal tril 0/-1e9, applied analytically
  const float* Wq = (const float*)d_in[4];
  const float* bq = (const float*)d_in[5];
  const float* Wk = (const float*)d_in[6];
  const float* bk = (const float*)d_in[7];
  const float* Wv = (const float*)d_in[8];
  const float* bv = (const float*)d_in[9];
  const float* Wo = (const float*)d_in[10];
  float* out   = (float*)d_out;
  float* probs = out + NOUT;
  char* ws = (char*)d_ws;
  short* hs_bf   = (short*)(ws + 0);
  short* attn_bf = hs_bf;                      // alias: hs dead after QKV GEMM
  short* wqkv_bf = (short*)(ws + 29360128LL);
  short* q_bf    = wqkv_bf;                    // alias: wqkv dead after QKV GEMM
  short* wo_bf   = (short*)(ws + 62390272LL);
  float* bias_qkv= (float*)(ws + 88080384LL);
  float* qkv     = (float*)(ws + 88098816LL);
  float* lfp     = (float*)(ws + 88098816LL);  // alias: qkv dead after vtrans
  short* k_bf    = (short*)(ws + 163596288LL);
  short* vt_bf   = (short*)(ws + 167790592LL);

  cast_bf16<<<2048, 256, 0, stream>>>(hs, hs_bf, 3670016LL);
  cast_bf16<<<2048, 256, 0, stream>>>(Wq, wqkv_bf, 3211264LL);
  cast_bf16<<<512, 256, 0, stream>>>(Wk, wqkv_bf + 12845056LL, 458752LL);
  cast_bf16<<<512, 256, 0, stream>>>(Wv, wqkv_bf + 14680064LL, 458752LL);
  cast_bf16<<<2048, 256, 0, stream>>>(Wo, wo_bf, 3211264LL);
  concat_bias<<<18, 256, 0, stream>>>(bq, bk, bv, bias_qkv);

  // fused QKV projection: (4096 x 4608) = hs(4096x3584) @ [Wq;Wk;Wv]^T + bias
  gemm_bias_f32<<<dim3(36, 32), 256, 0, stream>>>(hs_bf, wqkv_bf, qkv, bias_qkv, 3584, 4608);

  rope_qk<<<4096, 256, 0, stream>>>(qkv, cosb, sinb, q_bf, k_bf);
  vtrans<<<dim3(64, 4, 8), dim3(32, 8), 0, stream>>>(qkv, vt_bf);

  // unnorm P + row sums -> streaming normalize+zeros -> pipelined PV
  flash_scores<<<dim3(16, 56), 256, 0, stream>>>(q_bf, k_bf, probs, lfp);
  normalize_probs<<<28672, 256, 0, stream>>>(probs, lfp);
  pv_stream<<<dim3(32, 56), 256, 0, stream>>>(probs, vt_bf, attn_bf);

  // out = attn @ Wo^T
  gemm_bias_f32<<<dim3(28, 32), 256, 0, stream>>>(attn_bf, wo_bf, out, nullptr, 3584, 3584);
}

// Round 9
// 1077.596 us; speedup vs baseline: 1.3015x; 1.3015x over previous
//
#include <hip/hip_runtime.h>

// ---- problem constants -------------------------------------------------
#define Bn 2
#define Sn 2048
#define Hn 3584
#define NHn 28
#define NKVn 4
#define HDn 128
#define GROUPSn 7
#define SCALEF 0.08838834764831845f
#define NOUT 14680064LL /* B*S*H */

typedef __attribute__((ext_vector_type(4))) float f4v;
typedef __attribute__((ext_vector_type(16))) float f32x16;
typedef __attribute__((ext_vector_type(8))) short bf16x8;
typedef __attribute__((ext_vector_type(4))) short s16x4;

typedef __attribute__((address_space(1))) void gvoid;
typedef __attribute__((address_space(3))) void lvoid;
#define GLL16(g, l) __builtin_amdgcn_global_load_lds((gvoid*)(void*)(g), (lvoid*)(l), 16, 0, 0)

__device__ __forceinline__ short f2bf(float f) {
  unsigned u = __builtin_bit_cast(unsigned, f);
  u = (u + 0x7fffu + ((u >> 16) & 1u)) >> 16;  // RTNE
  return (short)u;
}

// ---- cast / small prep kernels ----------------------------------------
__global__ __launch_bounds__(256) void cast_bf16(const float* __restrict__ in,
                                                 short* __restrict__ out, long long n4) {
  long long i = (long long)blockIdx.x * 256 + threadIdx.x;
  long long stride = (long long)gridDim.x * 256;
  for (; i < n4; i += stride) {
    f4v f = ((const f4v*)in)[i];
    s16x4 o = { f2bf(f.x), f2bf(f.y), f2bf(f.z), f2bf(f.w) };
    ((s16x4*)out)[i] = o;
  }
}

__global__ __launch_bounds__(256) void concat_bias(const float* __restrict__ bq,
                                                   const float* __restrict__ bk,
                                                   const float* __restrict__ bv,
                                                   float* __restrict__ out) {
  int i = blockIdx.x * 256 + threadIdx.x;
  if (i < 3584) out[i] = bq[i];
  else if (i < 4096) out[i] = bk[i - 3584];
  else if (i < 4608) out[i] = bv[i - 4096];
}

// ---- shared 128x128 bf16 MFMA GEMM core (m97 structure, BK=32) --------
__device__ __forceinline__ void mm128_core(const short* __restrict__ Atile, long long lda,
                                           const short* __restrict__ Btile, long long ldb,
                                           int nk, short* lA, short* lB, f4v (&acc)[4][4]) {
  const int tid = threadIdx.x;
  const int lane = tid & 63;
  const int wr = (tid >> 6) >> 1, wc = (tid >> 6) & 1;
  const int srow = tid >> 2;
  const int scol = (tid & 3) * 8;
  const short* a0 = Atile + (long long)srow * lda + scol;
  const short* a1 = Atile + (long long)(srow + 64) * lda + scol;
  const short* b0 = Btile + (long long)srow * ldb + scol;
  const short* b1 = Btile + (long long)(srow + 64) * ldb + scol;
  short* la0 = lA + tid * 8;
  short* la1 = lA + (256 + tid) * 8;
  short* lb0 = lB + tid * 8;
  short* lb1 = lB + (256 + tid) * 8;
  const int fr = lane & 15;
  const int kc = (lane >> 4) * 8;
  for (int kt = 0; kt < nk; ++kt) {
    GLL16(a0 + kt * 32, la0);
    GLL16(a1 + kt * 32, la1);
    GLL16(b0 + kt * 32, lb0);
    GLL16(b1 + kt * 32, lb1);
    __syncthreads();
    bf16x8 af[4], bf[4];
#pragma unroll
    for (int m = 0; m < 4; ++m)
      af[m] = *(const bf16x8*)&lA[(wr * 64 + m * 16 + fr) * 32 + kc];
#pragma unroll
    for (int n = 0; n < 4; ++n)
      bf[n] = *(const bf16x8*)&lB[(wc * 64 + n * 16 + fr) * 32 + kc];
#pragma unroll
    for (int m = 0; m < 4; ++m)
#pragma unroll
      for (int n = 0; n < 4; ++n)
        acc[m][n] = __builtin_amdgcn_mfma_f32_16x16x32_bf16(af[m], bf[n], acc[m][n], 0, 0, 0);
    __syncthreads();
  }
}

// ---- GEMM with optional bias, fp32 out (QKV proj and Wo proj) ---------
__global__ __launch_bounds__(256) void gemm_bias_f32(const short* __restrict__ A,
                                                     const short* __restrict__ B,
                                                     float* __restrict__ C,
                                                     const float* __restrict__ bias,
                                                     int K, int N) {
  __shared__ alignas(16) short lA[4096];
  __shared__ alignas(16) short lB[4096];
  const long long brow = (long long)blockIdx.y * 128;
  const long long bcol = (long long)blockIdx.x * 128;
  f4v acc[4][4] = {};
  mm128_core(A + brow * K, K, B + bcol * K, K, K >> 5, lA, lB, acc);
  const int lane = threadIdx.x & 63;
  const int wr = (threadIdx.x >> 6) >> 1, wc = (threadIdx.x >> 6) & 1;
  const int rr = (lane >> 4) * 4, cc = lane & 15;
#pragma unroll
  for (int n = 0; n < 4; ++n) {
    long long col = bcol + wc * 64 + n * 16 + cc;
    float bv = bias ? bias[col] : 0.f;
#pragma unroll
    for (int m = 0; m < 4; ++m) {
#pragma unroll
      for (int j = 0; j < 4; ++j) {
        long long row = brow + wr * 64 + m * 16 + rr + j;
        C[row * N + col] = acc[m][n][j] + bv;
      }
    }
  }
}

// ---- RoPE on q,k (reads fp32 qkv, writes bf16 (b,h,s,d)) --------------
__global__ __launch_bounds__(256) void rope_qk(const float* __restrict__ qkv,
                                               const float* __restrict__ cosb,
                                               const float* __restrict__ sinb,
                                               short* __restrict__ qo,
                                               short* __restrict__ ko) {
  long long bs = blockIdx.x;              // 0..B*S-1
  int b = (int)(bs >> 11);
  int s = (int)(bs & 2047);
  const float* row = qkv + bs * 4608;
  const float* cp = cosb + bs * 128;
  const float* sp = sinb + bs * 128;
  for (int i = threadIdx.x; i < 4096; i += 256) {
    int d = i & 127;
    float c = cp[d], sn = sp[d];
    float x = row[i];
    float xr = (d < 64) ? -row[i + 64] : row[i - 64];
    short v = f2bf(x * c + xr * sn);
    if (i < 3584) {
      int h = i >> 7;
      qo[(((long long)(b * NHn + h) * Sn + s)) * HDn + d] = v;
    } else {
      int h = (i - 3584) >> 7;
      ko[(((long long)(b * NKVn + h) * Sn + s)) * HDn + d] = v;
    }
  }
}

// ---- v transpose: qkv fp32 v-section (b,s,kv,d) -> vT bf16 (b,kv,d,s) -
__global__ void vtrans(const float* __restrict__ qkv, short* __restrict__ vt) {
  __shared__ float tile[32][33];
  int bh = blockIdx.z;                    // b*NKV+kv
  int b = bh >> 2, h = bh & 3;
  int s0 = blockIdx.x * 32, d0 = blockIdx.y * 32;
  int tx = threadIdx.x, ty = threadIdx.y;  // 32 x 8
#pragma unroll
  for (int j = 0; j < 32; j += 8) {
    int s = s0 + ty + j;
    tile[ty + j][tx] = qkv[((long long)(b * Sn + s)) * 4608 + 4096 + h * 128 + d0 + tx];
  }
  __syncthreads();
#pragma unroll
  for (int j = 0; j < 32; j += 8) {
    int d = d0 + ty + j;
    vt[((long long)(bh * 128 + d)) * Sn + s0 + tx] = f2bf(tile[tx][ty + j]);
  }
}

// ---- zero strictly-upper probs tiles (nontemporal, full-BW) -----------
__global__ __launch_bounds__(256) void zero_upper(float* probs) {
  int ck = blockIdx.x, qb = blockIdx.y, bh = blockIdx.z;
  if (ck <= qb) return;
  float* base = probs + (long long)bh * ((long long)Sn * Sn) +
                (long long)qb * 128 * Sn + (long long)ck * 128;
  int tid = threadIdx.x;
  int r0 = tid >> 3;
  int c0 = tid & 7;
  f4v z = {0.f, 0.f, 0.f, 0.f};
  for (int rr = 0; rr < 128; rr += 32) {
    f4v* rowp = (f4v*)(base + (long long)(r0 + rr) * Sn);
#pragma unroll
    for (int c = 0; c < 4; ++c) __builtin_nontemporal_store(z, &rowp[c0 + c * 8]);
  }
}

// ---- fused attention: swapped-QK^T 32x32 MFMA, two-pass, in-reg PV ----
// Block = 128 q-rows of one (b,h); wave w owns q = w*32 + (lane&31) -- each
// lane owns ONE q row (swapped mfma: col=lane&31=q). Pass 1: QK^T + exp ->
// per-lane row sum (1 shfl_xor(32) reduce). Pass 2: recompute QK^T, write
// NORMALIZED P (f4v stores, lane-local invl), build PV A-frags in-register
// (4 shfl_xor(32) per 16-k chunk), accumulate O (normalized). No P re-read,
// no separate normalize pass, no pv kernel.
__global__ __launch_bounds__(256, 2) void fused_attn2(const short* __restrict__ Q,
                                                      const short* __restrict__ Kb,
                                                      const short* __restrict__ Vt,
                                                      float* __restrict__ probs,
                                                      short* __restrict__ attn) {
  __shared__ alignas(16) short lK[2][16384];   // 2 x 32 KB K tiles
  const int tid = threadIdx.x;
  const int w = tid >> 6;
  const int lane = tid & 63;
  const int lam = lane & 31, h = lane >> 5;
  const int qb = 15 - (int)blockIdx.x;         // heavy blocks first
  const int bh = blockIdx.y;
  const int b = bh / NHn, hh = bh - b * NHn, kv = hh / GROUPSn;
  const short* Qb = Q + (long long)bh * (Sn * HDn);
  const short* Kbb = Kb + (long long)(b * NKVn + kv) * (Sn * HDn);
  const short* Vb = Vt + (long long)(b * NKVn + kv) * (HDn * Sn);
  float* Pb = probs + (long long)bh * ((long long)Sn * Sn) + (long long)qb * 128 * Sn;
  const int qloc = w * 32 + lam;               // this lane's q row (0..127)

  // Q as B-frag (32x32x16): lane holds Q[q=lam][d = s*16 + h*8 + 0..7]
  bf16x8 qf[8];
  {
    const short* qr = Qb + (long long)(qb * 128 + qloc) * HDn + h * 8;
#pragma unroll
    for (int s = 0; s < 8; ++s) qf[s] = *(const bf16x8*)(qr + s * 16);
  }
  // K staging map: chunk M -> row M>>4, src chunk (M&15)^(row&15)
  int rsw[8], csw[8];
#pragma unroll
  for (int i = 0; i < 8; ++i) {
    int M = i * 256 + tid;
    rsw[i] = M >> 4;
    csw[i] = (M & 15) ^ (rsw[i] & 15);
  }
  const int c8base = lam & 15;                 // read-side xor (row&15 == lam&15)
  const int nkt = qb + 1;

#define STAGEK(BUF, KT) do {                                                      \
    const short* base_ = Kbb + (long long)(KT) * 128 * HDn;                       \
    _Pragma("unroll")                                                             \
    for (int i = 0; i < 8; ++i)                                                   \
      GLL16(base_ + (long long)rsw[i] * HDn + csw[i] * 8,                         \
            (short*)lK[BUF] + (i * 256 + tid) * 8);                               \
  } while (0)

  // K as A-frag: lane holds K[k = a*32+lam][d = s*16 + h*8 + 0..7]
#define QKT(ACCP, LCUR) do {                                                      \
    _Pragma("unroll")                                                             \
    for (int s = 0; s < 8; ++s) {                                                 \
      const int co_ = ((s * 2 + h) ^ c8base) * 8;                                 \
      _Pragma("unroll")                                                           \
      for (int a = 0; a < 4; ++a) {                                               \
        bf16x8 kf_ = *(const bf16x8*)&(LCUR)[(a * 32 + lam) * 128 + co_];         \
        ACCP[a] = __builtin_amdgcn_mfma_f32_32x32x16_bf16(kf_, qf[s], ACCP[a], 0, 0, 0); \
      }                                                                           \
    }                                                                             \
  } while (0)

  // -------- pass 1: row sums only --------
  float lsum = 0.f;
  STAGEK(0, 0);
  int cur = 0;
  for (int kt = 0; kt < nkt; ++kt) {
    __syncthreads();
    if (kt + 1 < nkt) STAGEK(cur ^ 1, kt + 1);
    const short* lcur = (const short*)lK[cur];
    f32x16 accp[4] = {};
    QKT(accp, lcur);
    const bool diag = (kt == qb);
#pragma unroll
    for (int a = 0; a < 4; ++a)
#pragma unroll
      for (int r = 0; r < 16; ++r) {
        int kloc = a * 32 + (r & 3) + 8 * (r >> 2) + 4 * h;
        float s = fminf(accp[a][r] * SCALEF, 60.f);
        float p = __expf(s);
        if (diag && kloc > qloc) p = 0.f;
        lsum += p;
      }
    cur ^= 1;
  }
  lsum += __shfl_xor(lsum, 32);                // lanes l, l^32 share q
  const float invl = 1.f / lsum;

  // -------- pass 2: normalized P write + in-register PV --------
  __syncthreads();                             // all waves done with lK
  STAGEK(0, 0);
  cur = 0;
  f32x16 acco[4] = {};
  for (int kt = 0; kt < nkt; ++kt) {
    __syncthreads();
    if (kt + 1 < nkt) STAGEK(cur ^ 1, kt + 1);
    const short* lcur = (const short*)lK[cur];
    f32x16 accp[4] = {};
    QKT(accp, lcur);
    const bool diag = (kt == qb);
    float* prow = Pb + (long long)qloc * Sn + kt * 128 + 4 * h;
    const short* vrow = Vb + (long long)lam * Sn + kt * 128 + h * 8;
#pragma unroll
    for (int a = 0; a < 4; ++a) {
      float pn[16];
#pragma unroll
      for (int r = 0; r < 16; ++r) {
        int kloc = a * 32 + (r & 3) + 8 * (r >> 2) + 4 * h;
        float s = fminf(accp[a][r] * SCALEF, 60.f);
        float p = __expf(s) * invl;
        if (diag && kloc > qloc) p = 0.f;
        pn[r] = p;
      }
      // normalized P store: reg quad 4T..4T+3 -> cols a*32 + 8T + 4h
#pragma unroll
      for (int T = 0; T < 4; ++T) {
        f4v v = { pn[4 * T], pn[4 * T + 1], pn[4 * T + 2], pn[4 * T + 3] };
        *(f4v*)(prow + a * 32 + 8 * T) = v;
      }
      // PV: build A-frags for k-chunks c = 2a, 2a+1 via xor-32 exchange
#pragma unroll
      for (int ci = 0; ci < 2; ++ci) {
        const int ro = ci * 8;
        float r0 = __shfl_xor(h ? pn[ro + 0] : pn[ro + 4], 32);
        float r1 = __shfl_xor(h ? pn[ro + 1] : pn[ro + 5], 32);
        float r2 = __shfl_xor(h ? pn[ro + 2] : pn[ro + 6], 32);
        float r3 = __shfl_xor(h ? pn[ro + 3] : pn[ro + 7], 32);
        float t0 = h ? r0 : pn[ro + 0];
        float t1 = h ? r1 : pn[ro + 1];
        float t2 = h ? r2 : pn[ro + 2];
        float t3 = h ? r3 : pn[ro + 3];
        float t4 = h ? pn[ro + 4] : r0;
        float t5 = h ? pn[ro + 5] : r1;
        float t6 = h ? pn[ro + 6] : r2;
        float t7 = h ? pn[ro + 7] : r3;
        bf16x8 pf = { f2bf(t0), f2bf(t1), f2bf(t2), f2bf(t3),
                      f2bf(t4), f2bf(t5), f2bf(t6), f2bf(t7) };
        const int c = a * 2 + ci;
#pragma unroll
        for (int f = 0; f < 4; ++f) {
          bf16x8 vf = *(const bf16x8*)(vrow + (long long)f * 32 * Sn + c * 16);
          acco[f] = __builtin_amdgcn_mfma_f32_32x32x16_bf16(pf, vf, acco[f], 0, 0, 0);
        }
      }
    }
    cur ^= 1;
  }
#undef QKT
#undef STAGEK

  // attn epilogue: O[q = w*32 + (r&3)+8(r>>2)+4h][d = f*32+lam], normalized
#pragma unroll
  for (int f = 0; f < 4; ++f)
#pragma unroll
    for (int r = 0; r < 16; ++r) {
      int qv = (r & 3) + 8 * (r >> 2) + 4 * h;
      long long q = (long long)qb * 128 + w * 32 + qv;
      attn[((long long)(b * Sn) + q) * Hn + hh * HDn + f * 32 + lam] = f2bf(acco[f][r]);
    }
}

// ---- workspace layout (bytes) -----------------------------------------
// hs_bf16   @ 0          (29,360,128)  -- reused later as attn_bf16
// wqkv_bf16 @ 29,360,128 (33,030,144)  -- reused later as q_bf16
// wo_bf16   @ 62,390,272 (25,690,112)
// bias_qkv  @ 88,080,384 (18,432)
// qkv_f32   @ 88,098,816 (75,497,472)
// k_bf16    @163,596,288 ( 4,194,304)
// vT_bf16   @167,790,592 ( 4,194,304)   total = 171,984,896 B

extern "C" void kernel_launch(void* const* d_in, const int* in_sizes, int n_in,
                              void* d_out, int out_size, void* d_ws, size_t ws_size,
                              hipStream_t stream) {
  const float* hs   = (const float*)d_in[0];
  const float* cosb = (const float*)d_in[1];
  const float* sinb = (const float*)d_in[2];
  // d_in[3] attention_mask: exact causal tril 0/-1e9, applied analytically
  const float* Wq = (const float*)d_in[4];
  const float* bq = (const float*)d_in[5];
  const float* Wk = (const float*)d_in[6];
  const float* bk = (const float*)d_in[7];
  const float* Wv = (const float*)d_in[8];
  const float* bv = (const float*)d_in[9];
  const float* Wo = (const float*)d_in[10];
  float* out   = (float*)d_out;
  float* probs = out + NOUT;
  char* ws = (char*)d_ws;
  short* hs_bf   = (short*)(ws + 0);
  short* attn_bf = hs_bf;                      // alias: hs dead after QKV GEMM
  short* wqkv_bf = (short*)(ws + 29360128LL);
  short* q_bf    = wqkv_bf;                    // alias: wqkv dead after QKV GEMM
  short* wo_bf   = (short*)(ws + 62390272LL);
  float* bias_qkv= (float*)(ws + 88080384LL);
  float* qkv     = (float*)(ws + 88098816LL);
  short* k_bf    = (short*)(ws + 163596288LL);
  short* vt_bf   = (short*)(ws + 167790592LL);

  cast_bf16<<<2048, 256, 0, stream>>>(hs, hs_bf, 3670016LL);
  cast_bf16<<<2048, 256, 0, stream>>>(Wq, wqkv_bf, 3211264LL);
  cast_bf16<<<512, 256, 0, stream>>>(Wk, wqkv_bf + 12845056LL, 458752LL);
  cast_bf16<<<512, 256, 0, stream>>>(Wv, wqkv_bf + 14680064LL, 458752LL);
  cast_bf16<<<2048, 256, 0, stream>>>(Wo, wo_bf, 3211264LL);
  concat_bias<<<18, 256, 0, stream>>>(bq, bk, bv, bias_qkv);

  // fused QKV projection: (4096 x 4608) = hs(4096x3584) @ [Wq;Wk;Wv]^T + bias
  gemm_bias_f32<<<dim3(36, 32), 256, 0, stream>>>(hs_bf, wqkv_bf, qkv, bias_qkv, 3584, 4608);

  rope_qk<<<4096, 256, 0, stream>>>(qkv, cosb, sinb, q_bf, k_bf);
  vtrans<<<dim3(64, 4, 8), dim3(32, 8), 0, stream>>>(qkv, vt_bf);

  // upper-triangle zeros + fully-fused attention (normalized P + attn)
  zero_upper<<<dim3(16, 16, 56), 256, 0, stream>>>(probs);
  fused_attn2<<<dim3(16, 56), 256, 0, stream>>>(q_bf, k_bf, vt_bf, probs, attn_bf);

  // out = attn @ Wo^T
  gemm_bias_f32<<<dim3(28, 32), 256, 0, stream>>>(attn_bf, wo_bf, out, nullptr, 3584, 3584);
}